// Round 2
// baseline (968.551 us; speedup 1.0000x reference)
//
#include <hip/hip_runtime.h>
#include <hip/hip_bf16.h>

typedef __bf16 bf16x8 __attribute__((ext_vector_type(8)));
typedef __bf16 bf16x4 __attribute__((ext_vector_type(4)));
typedef float  f32x4  __attribute__((ext_vector_type(4)));

#define GLOAD_LDS16(gp, lp) \
  __builtin_amdgcn_global_load_lds((const __attribute__((address_space(1))) void*)(gp), \
                                   (__attribute__((address_space(3))) void*)(lp), 16, 0, 0)

// ---------------- utility kernels ----------------

__global__ __launch_bounds__(256) void zero_f32(float* __restrict__ p, int n) {
  int i = (blockIdx.x * 256 + threadIdx.x) * 4;
  if (i < n) *(float4*)(p + i) = make_float4(0.f, 0.f, 0.f, 0.f);
}

__global__ __launch_bounds__(256) void cvt_f32_bf16(const float* __restrict__ in,
                                                    __bf16* __restrict__ out, long n) {
  long i = ((long)blockIdx.x * 256 + threadIdx.x) * 4;
  if (i >= n) return;
  float4 v = *(const float4*)(in + i);
  bf16x4 o;
  o[0] = (__bf16)v.x; o[1] = (__bf16)v.y; o[2] = (__bf16)v.z; o[3] = (__bf16)v.w;
  *(bf16x4*)(out + i) = o;
}

// W [K][N] f32 row-major  ->  WT [N][K] bf16 row-major
__global__ __launch_bounds__(256) void cvt_wT(const float* __restrict__ W,
                                              __bf16* __restrict__ WT, int K, int N) {
  __shared__ float t[32][33];
  int k0 = blockIdx.x * 32, n0 = blockIdx.y * 32;
  int tx = threadIdx.x, ty = threadIdx.y;   // block (32,8)
  #pragma unroll
  for (int i = 0; i < 32; i += 8)
    t[ty + i][tx] = W[(size_t)(k0 + ty + i) * N + n0 + tx];
  __syncthreads();
  #pragma unroll
  for (int i = 0; i < 32; i += 8)
    WT[(size_t)(n0 + ty + i) * K + k0 + tx] = (__bf16)t[tx][ty + i];
}

// ---------------- main GEMM:  C[M,N] = A[M,K] @ BT[N,K]^T ----------------
// 128x128 tile, BK=32, 256 threads (4 waves), mfma_f32_16x16x32_bf16.

enum { EPI_BF16 = 0, EPI_F32_BIAS = 1, EPI_BF16_SILU = 2, EPI_BF16_BIAS = 3 };

template <int EPI>
__global__ __launch_bounds__(256, 2)
void gemm_bt(const __bf16* __restrict__ A, const __bf16* __restrict__ B,
             void* __restrict__ Cout, const float* __restrict__ bias,
             int M, int N, int K) {
  __shared__ __bf16 sA[128 * 32];
  __shared__ __bf16 sB[128 * 32];
  const int tid = threadIdx.x;
  const int w = tid >> 6, l = tid & 63;
  const int brow = blockIdx.x * 128;
  const int bcol = blockIdx.y * 128;
  const int wr = (w >> 1) * 64, wc = (w & 1) * 64;
  const int lr = l & 15, lk = (l >> 4) * 8;
  const int sr = l >> 2, sc = (l & 3) * 8;   // staging: row-in-chunk, col8

  f32x4 acc[4][4] = {};

  for (int k0 = 0; k0 < K; k0 += 32) {
    #pragma unroll
    for (int ch = 0; ch < 2; ++ch) {
      int i = w * 2 + ch;
      int r = i * 16 + sr;
      GLOAD_LDS16(A + (size_t)(brow + r) * K + k0 + sc, sA + i * 512);
      GLOAD_LDS16(B + (size_t)(bcol + r) * K + k0 + sc, sB + i * 512);
    }
    __syncthreads();
    bf16x8 af[4], bf[4];
    #pragma unroll
    for (int m = 0; m < 4; ++m)
      af[m] = *(const bf16x8*)(sA + (wr + m * 16 + lr) * 32 + lk);
    #pragma unroll
    for (int n = 0; n < 4; ++n)
      bf[n] = *(const bf16x8*)(sB + (wc + n * 16 + lr) * 32 + lk);
    #pragma unroll
    for (int m = 0; m < 4; ++m)
      #pragma unroll
      for (int n = 0; n < 4; ++n)
        acc[m][n] = __builtin_amdgcn_mfma_f32_16x16x32_bf16(af[m], bf[n], acc[m][n], 0, 0, 0);
    __syncthreads();
  }

  #pragma unroll
  for (int m = 0; m < 4; ++m) {
    int row0 = brow + wr + m * 16 + (l >> 4) * 4;
    #pragma unroll
    for (int n = 0; n < 4; ++n) {
      int col = bcol + wc + n * 16 + lr;
      float bv = (EPI == EPI_BF16) ? 0.f : bias[col];
      #pragma unroll
      for (int j = 0; j < 4; ++j) {
        float v = acc[m][n][j];
        size_t off = (size_t)(row0 + j) * N + col;
        if (EPI == EPI_BF16) {
          ((__bf16*)Cout)[off] = (__bf16)v;
        } else if (EPI == EPI_F32_BIAS) {
          ((float*)Cout)[off] = v + bv;
        } else if (EPI == EPI_BF16_BIAS) {
          ((__bf16*)Cout)[off] = (__bf16)(v + bv);
        } else {
          float z = v + bv;
          ((__bf16*)Cout)[off] = (__bf16)(z / (1.f + __expf(-z)));
        }
      }
    }
  }
}

// ---------------- attention pieces (per batch; qkv_b is [4096][3072]) ----------------

// softmax over head dim (64) for q part, in place; scale = DH^-0.5 = 0.125
__global__ __launch_bounds__(256) void q_softmax(__bf16* __restrict__ qkv) {
  int wg = blockIdx.x * 4 + (threadIdx.x >> 6);
  int l = threadIdx.x & 63;
  int row = wg >> 4, h = wg & 15;
  __bf16* p = qkv + (size_t)row * 3072 + h * 64 + l;
  float v = (float)*p * 0.125f;
  float m = v;
  #pragma unroll
  for (int s = 32; s; s >>= 1) m = fmaxf(m, __shfl_xor(m, s));
  float e = __expf(v - m);
  float sum = e;
  #pragma unroll
  for (int s = 32; s; s >>= 1) sum += __shfl_xor(sum, s);
  *p = (__bf16)(e / sum);
}

// k part: elementwise exp in place + column sums S[c], c in [0,1024)
__global__ __launch_bounds__(256) void k_exp(__bf16* __restrict__ qkv, float* __restrict__ S) {
  int c = blockIdx.x * 256 + threadIdx.x;
  int n0 = blockIdx.y * 128;
  float sum = 0.f;
  __bf16* base = qkv + (size_t)n0 * 3072 + 1024 + c;
  for (int i = 0; i < 128; ++i) {
    __bf16* p = base + (size_t)i * 3072;
    float e = __expf((float)*p);
    __bf16 eb = (__bf16)e;
    *p = eb;
    sum += (float)eb;
  }
  atomicAdd(&S[c], sum);
}

// ctx[h][d][e] += sum_n q_sm[n,d] * ek[n,e]   (n-chunked over grid.y, fp32 atomic accumulate)
__global__ __launch_bounds__(256) void ctx_gemm(const __bf16* __restrict__ qkv,
                                                float* __restrict__ ctx) {
  int h = blockIdx.x;
  int k0base = blockIdx.y * 1024;
  __shared__ __bf16 sQ[64 * 32];  // [d][n_local]
  __shared__ __bf16 sK[64 * 32];  // [e][n_local]
  int tid = threadIdx.x, w = tid >> 6, l = tid & 63;
  int lr = l & 15, lk = (l >> 4) * 8;
  int srow = tid >> 3, scol = (tid & 7) * 8;
  f32x4 acc[4] = {};

  for (int kc = 0; kc < 1024; kc += 32) {
    size_t grow = (size_t)(k0base + kc + srow) * 3072;
    bf16x8 qv = *(const bf16x8*)(qkv + grow + h * 64 + scol);
    bf16x8 kv = *(const bf16x8*)(qkv + grow + 1024 + h * 64 + scol);
    __syncthreads();
    #pragma unroll
    for (int j = 0; j < 8; ++j) {
      sQ[(scol + j) * 32 + srow] = qv[j];
      sK[(scol + j) * 32 + srow] = kv[j];
    }
    __syncthreads();
    bf16x8 a = *(const bf16x8*)(sQ + (w * 16 + lr) * 32 + lk);
    #pragma unroll
    for (int n = 0; n < 4; ++n) {
      bf16x8 bb = *(const bf16x8*)(sK + (n * 16 + lr) * 32 + lk);
      acc[n] = __builtin_amdgcn_mfma_f32_16x16x32_bf16(a, bb, acc[n], 0, 0, 0);
    }
  }
  float* cbase = ctx + (size_t)h * 64 * 64;
  #pragma unroll
  for (int n = 0; n < 4; ++n) {
    int col = n * 16 + lr;
    #pragma unroll
    for (int j = 0; j < 4; ++j) {
      int row = w * 16 + (l >> 4) * 4 + j;
      atomicAdd(cbase + row * 64 + col, acc[n][j]);
    }
  }
}

// outpv_b[n, h*64+e] = (sum_d v[n,d] * ctx[h][d][e]) / S[h*64+e]
__global__ __launch_bounds__(256) void pv_gemm(const __bf16* __restrict__ qkv,
                                               const float* __restrict__ ctx,
                                               const float* __restrict__ S,
                                               __bf16* __restrict__ outpv) {
  int h = blockIdx.y;
  int row0 = blockIdx.x * 128;
  __shared__ __bf16 sC[64 * 64];  // ctxT [e][d]
  int tid = threadIdx.x;
  const float* cb = ctx + (size_t)h * 4096;
  for (int i = tid; i < 4096; i += 256) {
    int d = i >> 6, e = i & 63;
    sC[e * 64 + d] = (__bf16)cb[i];
  }
  __syncthreads();
  int w = tid >> 6, l = tid & 63;
  int lr = l & 15, lk = (l >> 4) * 8;
  f32x4 acc[2][4] = {};
  const __bf16* vbase = qkv + 2048 + h * 64;
  #pragma unroll
  for (int kk = 0; kk < 64; kk += 32) {
    #pragma unroll
    for (int m = 0; m < 2; ++m) {
      int r = row0 + w * 32 + m * 16 + lr;
      bf16x8 a = *(const bf16x8*)(vbase + (size_t)r * 3072 + kk + lk);
      #pragma unroll
      for (int n = 0; n < 4; ++n) {
        bf16x8 bb = *(const bf16x8*)(sC + (n * 16 + lr) * 64 + kk + lk);
        acc[m][n] = __builtin_amdgcn_mfma_f32_16x16x32_bf16(a, bb, acc[m][n], 0, 0, 0);
      }
    }
  }
  #pragma unroll
  for (int m = 0; m < 2; ++m) {
    int rb = row0 + w * 32 + m * 16 + (l >> 4) * 4;
    #pragma unroll
    for (int n = 0; n < 4; ++n) {
      int e = n * 16 + lr;
      float inv = 1.0f / S[h * 64 + e];
      #pragma unroll
      for (int j = 0; j < 4; ++j)
        outpv[(size_t)(rb + j) * 1024 + h * 64 + e] = (__bf16)(acc[m][n][j] * inv);
    }
  }
}

// ---------------- LayerNorm (row of 1024, bf16 in -> bf16 out) ----------------
__global__ __launch_bounds__(256) void layernorm_k(const __bf16* __restrict__ attn,
                                                   const float* __restrict__ g,
                                                   const float* __restrict__ beta,
                                                   __bf16* __restrict__ out) {
  int row = blockIdx.x;
  int t = threadIdx.x;
  bf16x4 v4 = *(const bf16x4*)(attn + (size_t)row * 1024 + t * 4);
  float v0 = (float)v4[0], v1 = (float)v4[1], v2 = (float)v4[2], v3 = (float)v4[3];
  float s = v0 + v1 + v2 + v3;
  float ss = v0 * v0 + v1 * v1 + v2 * v2 + v3 * v3;
  #pragma unroll
  for (int sh = 32; sh; sh >>= 1) { s += __shfl_xor(s, sh); ss += __shfl_xor(ss, sh); }
  __shared__ float red[8];
  int w = t >> 6, l = t & 63;
  if (l == 0) { red[w] = s; red[4 + w] = ss; }
  __syncthreads();
  s = red[0] + red[1] + red[2] + red[3];
  ss = red[4] + red[5] + red[6] + red[7];
  float mu = s * (1.f / 1024.f);
  float var = ss * (1.f / 1024.f) - mu * mu;
  float rstd = rsqrtf(var + 1e-5f);
  float4 gg = *(const float4*)(g + t * 4);
  float4 bb = *(const float4*)(beta + t * 4);
  bf16x4 o;
  o[0] = (__bf16)((v0 - mu) * rstd * gg.x + bb.x);
  o[1] = (__bf16)((v1 - mu) * rstd * gg.y + bb.y);
  o[2] = (__bf16)((v2 - mu) * rstd * gg.z + bb.z);
  o[3] = (__bf16)((v3 - mu) * rstd * gg.w + bb.w);
  *(bf16x4*)(out + (size_t)row * 1024 + t * 4) = o;
}

// ---------------- launch ----------------

extern "C" void kernel_launch(void* const* d_in, const int* in_sizes, int n_in,
                              void* d_out, int out_size, void* d_ws, size_t ws_size,
                              hipStream_t stream) {
  const float* x     = (const float*)d_in[0];
  const float* W_qkv = (const float*)d_in[1];
  const float* W_out = (const float*)d_in[2];
  const float* b_out = (const float*)d_in[3];
  const float* ln_g  = (const float*)d_in[4];
  const float* ln_b  = (const float*)d_in[5];
  const float* W1    = (const float*)d_in[6];
  const float* b1    = (const float*)d_in[7];
  const float* W2    = (const float*)d_in[8];
  const float* b2    = (const float*)d_in[9];

  char* ws = (char*)d_ws;
  size_t off = 0;
  auto alloc = [&](size_t bytes) { void* p = ws + off; off += (bytes + 255) & ~(size_t)255; return p; };

  // total peak: ~112.3 MiB
  __bf16* wqkvT = (__bf16*)alloc(3072ull * 1024 * 2);  //  6 MiB
  __bf16* woutT = (__bf16*)alloc(1024ull * 1024 * 2);  //  2 MiB
  __bf16* w1T   = (__bf16*)alloc(4096ull * 1024 * 2);  //  8 MiB
  __bf16* w2T   = (__bf16*)alloc(1024ull * 4096 * 2);  //  8 MiB
  float*  Sctx  = (float*)alloc(66560ull * 4);         //  S[1024] + ctx[16*4096]
  __bf16* xb    = (__bf16*)alloc(16384ull * 1024 * 2); // 32 MiB; reused: attn_bf16, fchunk
  __bf16* outpv = (__bf16*)alloc(16384ull * 1024 * 2); // 32 MiB; reused: hln
  __bf16* qkv_b = (__bf16*)alloc(4096ull * 3072 * 2);  // 24 MiB

  float* S   = Sctx;
  float* ctx = Sctx + 1024;
  __bf16* attn = xb;      // after all batches: xb dead
  __bf16* hln  = outpv;   // after W_out gemm: outpv dead
  __bf16* fchunk = xb;    // after layernorm: attn dead

  // weight conversion + x conversion
  cvt_f32_bf16<<<16384, 256, 0, stream>>>(x, xb, 16777216L);
  cvt_wT<<<dim3(32, 96), dim3(32, 8), 0, stream>>>(W_qkv, wqkvT, 1024, 3072);
  cvt_wT<<<dim3(32, 32), dim3(32, 8), 0, stream>>>(W_out, woutT, 1024, 1024);
  cvt_wT<<<dim3(32, 128), dim3(32, 8), 0, stream>>>(W1, w1T, 1024, 4096);
  cvt_wT<<<dim3(128, 32), dim3(32, 8), 0, stream>>>(W2, w2T, 4096, 1024);

  // attention, one batch at a time (keeps qkv to 24 MiB)
  for (int b = 0; b < 4; ++b) {
    const __bf16* xb_b = xb + (size_t)b * 4096 * 1024;
    gemm_bt<EPI_BF16><<<dim3(32, 24), 256, 0, stream>>>(xb_b, wqkvT, qkv_b, nullptr, 4096, 3072, 1024);
    zero_f32<<<65, 256, 0, stream>>>(Sctx, 66560);
    q_softmax<<<16384, 256, 0, stream>>>(qkv_b);
    k_exp<<<dim3(4, 32), 256, 0, stream>>>(qkv_b, S);
    ctx_gemm<<<dim3(16, 4), 256, 0, stream>>>(qkv_b, ctx);
    pv_gemm<<<dim3(32, 16), 256, 0, stream>>>(qkv_b, ctx, S, outpv + (size_t)b * 4096 * 1024);
  }

  // attn = outpv @ W_out + b_out   (bf16, overwrites xb region)
  gemm_bt<EPI_BF16_BIAS><<<dim3(128, 8), 256, 0, stream>>>(outpv, woutT, attn, b_out, 16384, 1024, 1024);
  layernorm_k<<<16384, 256, 0, stream>>>(attn, ln_g, ln_b, hln);

  // FFN in 4 row-chunks of 4096 (fchunk reuses xb region, 32 MiB)
  for (int c = 0; c < 4; ++c) {
    const __bf16* h_c = hln + (size_t)c * 4096 * 1024;
    float* out_c = (float*)d_out + (size_t)c * 4096 * 1024;
    gemm_bt<EPI_BF16_SILU><<<dim3(32, 32), 256, 0, stream>>>(h_c, w1T, fchunk, b1, 4096, 4096, 1024);
    gemm_bt<EPI_F32_BIAS><<<dim3(32, 8), 256, 0, stream>>>(fchunk, w2T, out_c, b2, 4096, 1024, 4096);
  }
}

// Round 3
// 652.682 us; speedup vs baseline: 1.4840x; 1.4840x over previous
//
#include <hip/hip_runtime.h>
#include <hip/hip_bf16.h>

typedef __bf16 bf16x8 __attribute__((ext_vector_type(8)));
typedef __bf16 bf16x4 __attribute__((ext_vector_type(4)));
typedef float  f32x4  __attribute__((ext_vector_type(4)));

#define GLOAD_LDS16(gp, lp) \
  __builtin_amdgcn_global_load_lds((const __attribute__((address_space(1))) void*)(gp), \
                                   (__attribute__((address_space(3))) void*)(lp), 16, 0, 0)

// ---------------- utility kernels ----------------

__global__ __launch_bounds__(256) void zero_f32(float* __restrict__ p, int n) {
  int i = (blockIdx.x * 256 + threadIdx.x) * 4;
  if (i < n) *(float4*)(p + i) = make_float4(0.f, 0.f, 0.f, 0.f);
}

__global__ __launch_bounds__(256) void cvt_f32_bf16(const float* __restrict__ in,
                                                    __bf16* __restrict__ out, long n) {
  long i = ((long)blockIdx.x * 256 + threadIdx.x) * 4;
  if (i >= n) return;
  float4 v = *(const float4*)(in + i);
  bf16x4 o;
  o[0] = (__bf16)v.x; o[1] = (__bf16)v.y; o[2] = (__bf16)v.z; o[3] = (__bf16)v.w;
  *(bf16x4*)(out + i) = o;
}

// W [K][N] f32 row-major  ->  WT [N][K] bf16 row-major
__global__ __launch_bounds__(256) void cvt_wT(const float* __restrict__ W,
                                              __bf16* __restrict__ WT, int K, int N) {
  __shared__ float t[32][33];
  int k0 = blockIdx.x * 32, n0 = blockIdx.y * 32;
  int tx = threadIdx.x, ty = threadIdx.y;   // block (32,8)
  #pragma unroll
  for (int i = 0; i < 32; i += 8)
    t[ty + i][tx] = W[(size_t)(k0 + ty + i) * N + n0 + tx];
  __syncthreads();
  #pragma unroll
  for (int i = 0; i < 32; i += 8)
    WT[(size_t)(n0 + ty + i) * K + k0 + tx] = (__bf16)t[tx][ty + i];
}

// ---------------- main GEMM:  C[M,N] = A[M,K] @ BT[N,K]^T ----------------
// 128x128 tile, BK=32, 256 threads (4 waves), mfma_f32_16x16x32_bf16.

enum { EPI_BF16 = 0, EPI_F32_BIAS = 1, EPI_BF16_SILU = 2, EPI_BF16_BIAS = 3 };

template <int EPI>
__global__ __launch_bounds__(256, 2)
void gemm_bt(const __bf16* __restrict__ A, const __bf16* __restrict__ B,
             void* __restrict__ Cout, const float* __restrict__ bias,
             int M, int N, int K) {
  __shared__ __bf16 sA[128 * 32];
  __shared__ __bf16 sB[128 * 32];
  const int tid = threadIdx.x;
  const int w = tid >> 6, l = tid & 63;
  const int brow = blockIdx.x * 128;
  const int bcol = blockIdx.y * 128;
  const int wr = (w >> 1) * 64, wc = (w & 1) * 64;
  const int lr = l & 15, lk = (l >> 4) * 8;
  const int sr = l >> 2, sc = (l & 3) * 8;   // staging: row-in-chunk, col8

  f32x4 acc[4][4] = {};

  for (int k0 = 0; k0 < K; k0 += 32) {
    #pragma unroll
    for (int ch = 0; ch < 2; ++ch) {
      int i = w * 2 + ch;
      int r = i * 16 + sr;
      GLOAD_LDS16(A + (size_t)(brow + r) * K + k0 + sc, sA + i * 512);
      GLOAD_LDS16(B + (size_t)(bcol + r) * K + k0 + sc, sB + i * 512);
    }
    __syncthreads();
    bf16x8 af[4], bf[4];
    #pragma unroll
    for (int m = 0; m < 4; ++m)
      af[m] = *(const bf16x8*)(sA + (wr + m * 16 + lr) * 32 + lk);
    #pragma unroll
    for (int n = 0; n < 4; ++n)
      bf[n] = *(const bf16x8*)(sB + (wc + n * 16 + lr) * 32 + lk);
    #pragma unroll
    for (int m = 0; m < 4; ++m)
      #pragma unroll
      for (int n = 0; n < 4; ++n)
        acc[m][n] = __builtin_amdgcn_mfma_f32_16x16x32_bf16(af[m], bf[n], acc[m][n], 0, 0, 0);
    __syncthreads();
  }

  #pragma unroll
  for (int m = 0; m < 4; ++m) {
    int row0 = brow + wr + m * 16 + (l >> 4) * 4;
    #pragma unroll
    for (int n = 0; n < 4; ++n) {
      int col = bcol + wc + n * 16 + lr;
      float bv = (EPI == EPI_BF16) ? 0.f : bias[col];
      #pragma unroll
      for (int j = 0; j < 4; ++j) {
        float v = acc[m][n][j];
        size_t off = (size_t)(row0 + j) * N + col;
        if (EPI == EPI_BF16) {
          ((__bf16*)Cout)[off] = (__bf16)v;
        } else if (EPI == EPI_F32_BIAS) {
          ((float*)Cout)[off] = v + bv;
        } else if (EPI == EPI_BF16_BIAS) {
          ((__bf16*)Cout)[off] = (__bf16)(v + bv);
        } else {
          float z = v + bv;
          ((__bf16*)Cout)[off] = (__bf16)(z / (1.f + __expf(-z)));
        }
      }
    }
  }
}

// ---------------- attention pieces ----------------
// All take a batch index from blockIdx.z (z=0 == per-batch pointers, validated path).

// softmax over head dim (64) for q part, in place; scale = DH^-0.5 = 0.125
__global__ __launch_bounds__(256) void q_softmax(__bf16* __restrict__ qkv) {
  qkv += (size_t)blockIdx.z * 4096 * 3072;
  int wg = blockIdx.x * 4 + (threadIdx.x >> 6);
  int l = threadIdx.x & 63;
  int row = wg >> 4, h = wg & 15;
  __bf16* p = qkv + (size_t)row * 3072 + h * 64 + l;
  float v = (float)*p * 0.125f;
  float m = v;
  #pragma unroll
  for (int s = 32; s; s >>= 1) m = fmaxf(m, __shfl_xor(m, s));
  float e = __expf(v - m);
  float sum = e;
  #pragma unroll
  for (int s = 32; s; s >>= 1) sum += __shfl_xor(sum, s);
  *p = (__bf16)(e / sum);
}

// k part: elementwise exp in place + column sums S[c], c in [0,1024)
__global__ __launch_bounds__(256) void k_exp(__bf16* __restrict__ qkv, float* __restrict__ S) {
  qkv += (size_t)blockIdx.z * 4096 * 3072;
  S   += (size_t)blockIdx.z * 1024;
  int c = blockIdx.x * 256 + threadIdx.x;
  int n0 = blockIdx.y * 128;
  float sum = 0.f;
  __bf16* base = qkv + (size_t)n0 * 3072 + 1024 + c;
  for (int i = 0; i < 128; ++i) {
    __bf16* p = base + (size_t)i * 3072;
    float e = __expf((float)*p);
    __bf16 eb = (__bf16)e;
    *p = eb;
    sum += (float)eb;
  }
  atomicAdd(&S[c], sum);
}

// ctx[h][d][e] += sum_n q_sm[n,d] * ek[n,e]   (n-chunked over grid.y, fp32 atomic accumulate)
__global__ __launch_bounds__(256) void ctx_gemm(const __bf16* __restrict__ qkv,
                                                float* __restrict__ ctx) {
  qkv += (size_t)blockIdx.z * 4096 * 3072;
  ctx += (size_t)blockIdx.z * 16 * 4096;
  int h = blockIdx.x;
  int k0base = blockIdx.y * 1024;
  __shared__ __bf16 sQ[64 * 32];  // [d][n_local]
  __shared__ __bf16 sK[64 * 32];  // [e][n_local]
  int tid = threadIdx.x, w = tid >> 6, l = tid & 63;
  int lr = l & 15, lk = (l >> 4) * 8;
  int srow = tid >> 3, scol = (tid & 7) * 8;
  f32x4 acc[4] = {};

  for (int kc = 0; kc < 1024; kc += 32) {
    size_t grow = (size_t)(k0base + kc + srow) * 3072;
    bf16x8 qv = *(const bf16x8*)(qkv + grow + h * 64 + scol);
    bf16x8 kv = *(const bf16x8*)(qkv + grow + 1024 + h * 64 + scol);
    __syncthreads();
    #pragma unroll
    for (int j = 0; j < 8; ++j) {
      sQ[(scol + j) * 32 + srow] = qv[j];
      sK[(scol + j) * 32 + srow] = kv[j];
    }
    __syncthreads();
    bf16x8 a = *(const bf16x8*)(sQ + (w * 16 + lr) * 32 + lk);
    #pragma unroll
    for (int n = 0; n < 4; ++n) {
      bf16x8 bb = *(const bf16x8*)(sK + (n * 16 + lr) * 32 + lk);
      acc[n] = __builtin_amdgcn_mfma_f32_16x16x32_bf16(a, bb, acc[n], 0, 0, 0);
    }
  }
  float* cbase = ctx + (size_t)h * 64 * 64;
  #pragma unroll
  for (int n = 0; n < 4; ++n) {
    int col = n * 16 + lr;
    #pragma unroll
    for (int j = 0; j < 4; ++j) {
      int row = w * 16 + (l >> 4) * 4 + j;
      atomicAdd(cbase + row * 64 + col, acc[n][j]);
    }
  }
}

// outpv[n, h*64+e] = (sum_d v[n,d] * ctx[h][d][e]) / S[h*64+e]
__global__ __launch_bounds__(256) void pv_gemm(const __bf16* __restrict__ qkv,
                                               const float* __restrict__ ctx,
                                               const float* __restrict__ S,
                                               __bf16* __restrict__ outpv) {
  qkv   += (size_t)blockIdx.z * 4096 * 3072;
  ctx   += (size_t)blockIdx.z * 16 * 4096;
  S     += (size_t)blockIdx.z * 1024;
  outpv += (size_t)blockIdx.z * 4096 * 1024;
  int h = blockIdx.y;
  int row0 = blockIdx.x * 128;
  __shared__ __bf16 sC[64 * 64];  // ctxT [e][d]
  int tid = threadIdx.x;
  const float* cb = ctx + (size_t)h * 4096;
  for (int i = tid; i < 4096; i += 256) {
    int d = i >> 6, e = i & 63;
    sC[e * 64 + d] = (__bf16)cb[i];
  }
  __syncthreads();
  int w = tid >> 6, l = tid & 63;
  int lr = l & 15, lk = (l >> 4) * 8;
  f32x4 acc[2][4] = {};
  const __bf16* vbase = qkv + 2048 + h * 64;
  #pragma unroll
  for (int kk = 0; kk < 64; kk += 32) {
    #pragma unroll
    for (int m = 0; m < 2; ++m) {
      int r = row0 + w * 32 + m * 16 + lr;
      bf16x8 a = *(const bf16x8*)(vbase + (size_t)r * 3072 + kk + lk);
      #pragma unroll
      for (int n = 0; n < 4; ++n) {
        bf16x8 bb = *(const bf16x8*)(sC + (n * 16 + lr) * 64 + kk + lk);
        acc[m][n] = __builtin_amdgcn_mfma_f32_16x16x32_bf16(a, bb, acc[m][n], 0, 0, 0);
      }
    }
  }
  #pragma unroll
  for (int m = 0; m < 2; ++m) {
    int rb = row0 + w * 32 + m * 16 + (l >> 4) * 4;
    #pragma unroll
    for (int n = 0; n < 4; ++n) {
      int e = n * 16 + lr;
      float inv = 1.0f / S[h * 64 + e];
      #pragma unroll
      for (int j = 0; j < 4; ++j)
        outpv[(size_t)(rb + j) * 1024 + h * 64 + e] = (__bf16)(acc[m][n][j] * inv);
    }
  }
}

// ---------------- LayerNorm (row of 1024, bf16 in -> bf16 out) ----------------
__global__ __launch_bounds__(256) void layernorm_k(const __bf16* __restrict__ attn,
                                                   const float* __restrict__ g,
                                                   const float* __restrict__ beta,
                                                   __bf16* __restrict__ out) {
  int row = blockIdx.x;
  int t = threadIdx.x;
  bf16x4 v4 = *(const bf16x4*)(attn + (size_t)row * 1024 + t * 4);
  float v0 = (float)v4[0], v1 = (float)v4[1], v2 = (float)v4[2], v3 = (float)v4[3];
  float s = v0 + v1 + v2 + v3;
  float ss = v0 * v0 + v1 * v1 + v2 * v2 + v3 * v3;
  #pragma unroll
  for (int sh = 32; sh; sh >>= 1) { s += __shfl_xor(s, sh); ss += __shfl_xor(ss, sh); }
  __shared__ float red[8];
  int w = t >> 6, l = t & 63;
  if (l == 0) { red[w] = s; red[4 + w] = ss; }
  __syncthreads();
  s = red[0] + red[1] + red[2] + red[3];
  ss = red[4] + red[5] + red[6] + red[7];
  float mu = s * (1.f / 1024.f);
  float var = ss * (1.f / 1024.f) - mu * mu;
  float rstd = rsqrtf(var + 1e-5f);
  float4 gg = *(const float4*)(g + t * 4);
  float4 bb = *(const float4*)(beta + t * 4);
  bf16x4 o;
  o[0] = (__bf16)((v0 - mu) * rstd * gg.x + bb.x);
  o[1] = (__bf16)((v1 - mu) * rstd * gg.y + bb.y);
  o[2] = (__bf16)((v2 - mu) * rstd * gg.z + bb.z);
  o[3] = (__bf16)((v3 - mu) * rstd * gg.w + bb.w);
  *(bf16x4*)(out + (size_t)row * 1024 + t * 4) = o;
}

// ---------------- launch ----------------

extern "C" void kernel_launch(void* const* d_in, const int* in_sizes, int n_in,
                              void* d_out, int out_size, void* d_ws, size_t ws_size,
                              hipStream_t stream) {
  const float* x     = (const float*)d_in[0];
  const float* W_qkv = (const float*)d_in[1];
  const float* W_out = (const float*)d_in[2];
  const float* b_out = (const float*)d_in[3];
  const float* ln_g  = (const float*)d_in[4];
  const float* ln_b  = (const float*)d_in[5];
  const float* W1    = (const float*)d_in[6];
  const float* b1    = (const float*)d_in[7];
  const float* W2    = (const float*)d_in[8];
  const float* b2    = (const float*)d_in[9];

  char* ws = (char*)d_ws;
  size_t off = 0;
  auto alloc = [&](size_t bytes) { void* p = ws + off; off += (bytes + 255) & ~(size_t)255; return p; };

  // Weights (both paths): 24 MiB
  __bf16* wqkvT = (__bf16*)alloc(3072ull * 1024 * 2);
  __bf16* woutT = (__bf16*)alloc(1024ull * 1024 * 2);
  __bf16* w1T   = (__bf16*)alloc(4096ull * 1024 * 2);
  __bf16* w2T   = (__bf16*)alloc(1024ull * 4096 * 2);

  cvt_wT<<<dim3(32, 96), dim3(32, 8), 0, stream>>>(W_qkv, wqkvT, 1024, 3072);
  cvt_wT<<<dim3(32, 32), dim3(32, 8), 0, stream>>>(W_out, woutT, 1024, 1024);
  cvt_wT<<<dim3(32, 128), dim3(32, 8), 0, stream>>>(W1, w1T, 1024, 4096);
  cvt_wT<<<dim3(128, 32), dim3(32, 8), 0, stream>>>(W2, w2T, 4096, 1024);

  const size_t FULL_NEED = 196ull << 20;   // ~186 MiB used; margin

  if (ws_size >= FULL_NEED) {
    // ---------- FULL path: every GEMM at full M=16384 ----------
    float*  Sctx  = (float*)alloc((4096ull + 4 * 16 * 4096) * 4);  // S[4][1024], ctx[4][16][4096]
    __bf16* xb    = (__bf16*)alloc(16384ull * 1024 * 2);  // 32 MiB; later: hln
    __bf16* qkv   = (__bf16*)alloc(16384ull * 3072 * 2);  // 96 MiB; tail reused: attn
    __bf16* outpv = (__bf16*)alloc(16384ull * 1024 * 2);  // 32 MiB (contiguous after qkv)

    float* S   = Sctx;
    float* ctx = Sctx + 4096;
    __bf16* attn = (__bf16*)((char*)qkv + (64ull << 20)); // qkv tail (dead after pv_gemm)
    __bf16* hln  = xb;                                    // xb dead after QKV gemm
    __bf16* ffn1 = qkv;                                   // spans qkv+outpv (128 MiB), both dead

    cvt_f32_bf16<<<16384, 256, 0, stream>>>(x, xb, 16777216L);
    zero_f32<<<260, 256, 0, stream>>>(Sctx, 266240);

    gemm_bt<EPI_BF16><<<dim3(128, 24), 256, 0, stream>>>(xb, wqkvT, qkv, nullptr, 16384, 3072, 1024);
    q_softmax<<<dim3(16384, 1, 4), 256, 0, stream>>>(qkv);
    k_exp<<<dim3(4, 32, 4), 256, 0, stream>>>(qkv, S);
    ctx_gemm<<<dim3(16, 4, 4), 256, 0, stream>>>(qkv, ctx);
    pv_gemm<<<dim3(32, 16, 4), 256, 0, stream>>>(qkv, ctx, S, outpv);

    gemm_bt<EPI_BF16_BIAS><<<dim3(128, 8), 256, 0, stream>>>(outpv, woutT, attn, b_out, 16384, 1024, 1024);
    layernorm_k<<<16384, 256, 0, stream>>>(attn, ln_g, ln_b, hln);
    gemm_bt<EPI_BF16_SILU><<<dim3(128, 32), 256, 0, stream>>>(hln, w1T, ffn1, b1, 16384, 4096, 1024);
    gemm_bt<EPI_F32_BIAS><<<dim3(128, 8), 256, 0, stream>>>(ffn1, w2T, (float*)d_out, b2, 16384, 1024, 4096);
  } else {
    // ---------- CHUNKED fallback (validated round-2 path, ~112 MiB) ----------
    float*  Sctx  = (float*)alloc(66560ull * 4);
    __bf16* xb    = (__bf16*)alloc(16384ull * 1024 * 2);
    __bf16* outpv = (__bf16*)alloc(16384ull * 1024 * 2);
    __bf16* qkv_b = (__bf16*)alloc(4096ull * 3072 * 2);

    float* S   = Sctx;
    float* ctx = Sctx + 1024;
    __bf16* attn = xb;
    __bf16* hln  = outpv;
    __bf16* fchunk = xb;

    cvt_f32_bf16<<<16384, 256, 0, stream>>>(x, xb, 16777216L);

    for (int b = 0; b < 4; ++b) {
      const __bf16* xb_b = xb + (size_t)b * 4096 * 1024;
      gemm_bt<EPI_BF16><<<dim3(32, 24), 256, 0, stream>>>(xb_b, wqkvT, qkv_b, nullptr, 4096, 3072, 1024);
      zero_f32<<<65, 256, 0, stream>>>(Sctx, 66560);
      q_softmax<<<dim3(16384, 1, 1), 256, 0, stream>>>(qkv_b);
      k_exp<<<dim3(4, 32, 1), 256, 0, stream>>>(qkv_b, S);
      ctx_gemm<<<dim3(16, 4, 1), 256, 0, stream>>>(qkv_b, ctx);
      pv_gemm<<<dim3(32, 16, 1), 256, 0, stream>>>(qkv_b, ctx, S, outpv + (size_t)b * 4096 * 1024);
    }

    gemm_bt<EPI_BF16_BIAS><<<dim3(128, 8), 256, 0, stream>>>(outpv, woutT, attn, b_out, 16384, 1024, 1024);
    layernorm_k<<<16384, 256, 0, stream>>>(attn, ln_g, ln_b, hln);

    for (int c = 0; c < 4; ++c) {
      const __bf16* h_c = hln + (size_t)c * 4096 * 1024;
      float* out_c = (float*)d_out + (size_t)c * 4096 * 1024;
      gemm_bt<EPI_BF16_SILU><<<dim3(32, 32), 256, 0, stream>>>(h_c, w1T, fchunk, b1, 4096, 4096, 1024);
      gemm_bt<EPI_F32_BIAS><<<dim3(32, 8), 256, 0, stream>>>(fchunk, w2T, out_c, b2, 4096, 1024, 4096);
    }
  }
}

// Round 4
// 593.182 us; speedup vs baseline: 1.6328x; 1.1003x over previous
//
#include <hip/hip_runtime.h>
#include <hip/hip_bf16.h>

typedef __bf16 bf16x8 __attribute__((ext_vector_type(8)));
typedef __bf16 bf16x4 __attribute__((ext_vector_type(4)));
typedef float  f32x4  __attribute__((ext_vector_type(4)));

#define SWZ 1

#define GLOAD_LDS16(gp, lp) \
  __builtin_amdgcn_global_load_lds((const __attribute__((address_space(1))) void*)(gp), \
                                   (__attribute__((address_space(3))) void*)(lp), 16, 0, 0)

// ---------------- utility kernels ----------------

__global__ __launch_bounds__(256) void zero_f32(float* __restrict__ p, int n) {
  int i = (blockIdx.x * 256 + threadIdx.x) * 4;
  if (i < n) *(float4*)(p + i) = make_float4(0.f, 0.f, 0.f, 0.f);
}

__global__ __launch_bounds__(256) void cvt_f32_bf16(const float* __restrict__ in,
                                                    __bf16* __restrict__ out, long n) {
  long i = ((long)blockIdx.x * 256 + threadIdx.x) * 4;
  if (i >= n) return;
  float4 v = *(const float4*)(in + i);
  bf16x4 o;
  o[0] = (__bf16)v.x; o[1] = (__bf16)v.y; o[2] = (__bf16)v.z; o[3] = (__bf16)v.w;
  *(bf16x4*)(out + i) = o;
}

// W [K][N] f32 row-major  ->  WT [N][K] bf16 row-major
__global__ __launch_bounds__(256) void cvt_wT(const float* __restrict__ W,
                                              __bf16* __restrict__ WT, int K, int N) {
  __shared__ float t[32][33];
  int k0 = blockIdx.x * 32, n0 = blockIdx.y * 32;
  int tx = threadIdx.x, ty = threadIdx.y;   // block (32,8)
  #pragma unroll
  for (int i = 0; i < 32; i += 8)
    t[ty + i][tx] = W[(size_t)(k0 + ty + i) * N + n0 + tx];
  __syncthreads();
  #pragma unroll
  for (int i = 0; i < 32; i += 8)
    WT[(size_t)(n0 + ty + i) * K + k0 + tx] = (__bf16)t[tx][ty + i];
}

// ---------------- 256x256 deep-pipelined GEMM:  C[M,N] = A[M,K] @ BT[N,K]^T ----
// 512 threads (8 waves 2x4), BK=32, quad-buffered LDS (128 KiB), counted vmcnt,
// raw barriers, setprio around MFMA clusters, T2 octet-XOR swizzle.

enum { EPI_BF16 = 0, EPI_F32_BIAS = 1, EPI_BF16_SILU = 2, EPI_BF16_BIAS = 3 };

// stage one 256x32 A-panel + 256x32 B-panel into lds buf (linear dest, pre-swizzled src)
__device__ __forceinline__ void stage_tile(const __bf16* __restrict__ A,
                                           const __bf16* __restrict__ B,
                                           __bf16* sAB,  // A at +0, B at +8192
                                           int brow, int bcol, int K, int k0,
                                           int w, int l) {
  int rr = w * 16 + (l >> 2);        // row 0..127 within half
  int oct = l & 3;                   // 16B col-octet
#if SWZ
  int c = (oct ^ (rr & 3)) * 8;      // pre-swizzled global octet
#else
  int c = oct * 8;
#endif
  GLOAD_LDS16(A + (size_t)(brow + rr) * K + k0 + c,       sAB + w * 512);
  GLOAD_LDS16(A + (size_t)(brow + 128 + rr) * K + k0 + c, sAB + 4096 + w * 512);
  GLOAD_LDS16(B + (size_t)(bcol + rr) * K + k0 + c,       sAB + 8192 + w * 512);
  GLOAD_LDS16(B + (size_t)(bcol + 128 + rr) * K + k0 + c, sAB + 12288 + w * 512);
}

template <int EPI>
__global__ __launch_bounds__(512, 1)
void gemm256(const __bf16* __restrict__ A, const __bf16* __restrict__ B,
             void* __restrict__ Cout, const float* __restrict__ bias,
             int M, int N, int K) {
  __shared__ __bf16 lds[4 * 16384];   // 4 bufs x (A 8192 + B 8192) elems = 128 KiB
  const int tid = threadIdx.x;
  const int w = tid >> 6, l = tid & 63;
  const int brow = blockIdx.x * 256;
  const int bcol = blockIdx.y * 256;
  const int wr = w >> 2, wc = w & 3;           // wave grid 2x4
  const int lr = l & 15, lk = (l >> 4) * 8;
#if SWZ
  const int rdo = ((lk >> 3) ^ (lr & 3)) << 3; // swizzled read octet (row&3 == lr&3)
#else
  const int rdo = lk;
#endif
  const int NT = K >> 5;

  f32x4 acc[8][4] = {};

  // prologue: stage tiles 0,1,2
  stage_tile(A, B, lds,           brow, bcol, K, 0,  w, l);
  stage_tile(A, B, lds + 16384,   brow, bcol, K, 32, w, l);
  stage_tile(A, B, lds + 32768,   brow, bcol, K, 64, w, l);

  for (int t = 0; t < NT; ++t) {
    if (t + 2 < NT)      asm volatile("s_waitcnt vmcnt(8)" ::: "memory");
    else if (t + 1 < NT) asm volatile("s_waitcnt vmcnt(4)" ::: "memory");
    else                 asm volatile("s_waitcnt vmcnt(0)" ::: "memory");
    __builtin_amdgcn_s_barrier();
    if (t + 3 < NT)
      stage_tile(A, B, lds + ((t + 3) & 3) * 16384, brow, bcol, K, (t + 3) * 32, w, l);

    const __bf16* sA = lds + (t & 3) * 16384;
    const __bf16* sB = sA + 8192;

    bf16x8 bfr[4], afr[4];
    #pragma unroll
    for (int n = 0; n < 4; ++n)
      bfr[n] = *(const bf16x8*)(sB + (wc * 64 + n * 16 + lr) * 32 + rdo);
    #pragma unroll
    for (int m = 0; m < 4; ++m)
      afr[m] = *(const bf16x8*)(sA + (wr * 128 + m * 16 + lr) * 32 + rdo);

    __builtin_amdgcn_s_setprio(1);
    #pragma unroll
    for (int m = 0; m < 4; ++m)
      #pragma unroll
      for (int n = 0; n < 4; ++n)
        acc[m][n] = __builtin_amdgcn_mfma_f32_16x16x32_bf16(afr[m], bfr[n], acc[m][n], 0, 0, 0);
    __builtin_amdgcn_s_setprio(0);

    #pragma unroll
    for (int m = 0; m < 4; ++m)
      afr[m] = *(const bf16x8*)(sA + (wr * 128 + (m + 4) * 16 + lr) * 32 + rdo);

    __builtin_amdgcn_s_setprio(1);
    #pragma unroll
    for (int m = 0; m < 4; ++m)
      #pragma unroll
      for (int n = 0; n < 4; ++n)
        acc[m + 4][n] = __builtin_amdgcn_mfma_f32_16x16x32_bf16(afr[m], bfr[n], acc[m + 4][n], 0, 0, 0);
    __builtin_amdgcn_s_setprio(0);
  }

  // epilogue
  #pragma unroll
  for (int m = 0; m < 8; ++m) {
    int row0 = brow + wr * 128 + m * 16 + (l >> 4) * 4;
    #pragma unroll
    for (int n = 0; n < 4; ++n) {
      int col = bcol + wc * 64 + n * 16 + lr;
      float bv = (EPI == EPI_BF16) ? 0.f : bias[col];
      #pragma unroll
      for (int j = 0; j < 4; ++j) {
        float v = acc[m][n][j];
        size_t off = (size_t)(row0 + j) * N + col;
        if (EPI == EPI_BF16) {
          ((__bf16*)Cout)[off] = (__bf16)v;
        } else if (EPI == EPI_F32_BIAS) {
          ((float*)Cout)[off] = v + bv;
        } else if (EPI == EPI_BF16_BIAS) {
          ((__bf16*)Cout)[off] = (__bf16)(v + bv);
        } else {
          float z = v + bv;
          ((__bf16*)Cout)[off] = (__bf16)(z / (1.f + __expf(-z)));
        }
      }
    }
  }
}

// ---------------- attention pieces ----------------
// All take a batch index from blockIdx.z (z=0 == per-batch pointers, validated path).

__global__ __launch_bounds__(256) void q_softmax(__bf16* __restrict__ qkv) {
  qkv += (size_t)blockIdx.z * 4096 * 3072;
  int wg = blockIdx.x * 4 + (threadIdx.x >> 6);
  int l = threadIdx.x & 63;
  int row = wg >> 4, h = wg & 15;
  __bf16* p = qkv + (size_t)row * 3072 + h * 64 + l;
  float v = (float)*p * 0.125f;
  float m = v;
  #pragma unroll
  for (int s = 32; s; s >>= 1) m = fmaxf(m, __shfl_xor(m, s));
  float e = __expf(v - m);
  float sum = e;
  #pragma unroll
  for (int s = 32; s; s >>= 1) sum += __shfl_xor(sum, s);
  *p = (__bf16)(e / sum);
}

__global__ __launch_bounds__(256) void k_exp(__bf16* __restrict__ qkv, float* __restrict__ S) {
  qkv += (size_t)blockIdx.z * 4096 * 3072;
  S   += (size_t)blockIdx.z * 1024;
  int c = blockIdx.x * 256 + threadIdx.x;
  int n0 = blockIdx.y * 128;
  float sum = 0.f;
  __bf16* base = qkv + (size_t)n0 * 3072 + 1024 + c;
  for (int i = 0; i < 128; ++i) {
    __bf16* p = base + (size_t)i * 3072;
    float e = __expf((float)*p);
    __bf16 eb = (__bf16)e;
    *p = eb;
    sum += (float)eb;
  }
  atomicAdd(&S[c], sum);
}

__global__ __launch_bounds__(256) void ctx_gemm(const __bf16* __restrict__ qkv,
                                                float* __restrict__ ctx) {
  qkv += (size_t)blockIdx.z * 4096 * 3072;
  ctx += (size_t)blockIdx.z * 16 * 4096;
  int h = blockIdx.x;
  int k0base = blockIdx.y * 1024;
  __shared__ __bf16 sQ[64 * 32];
  __shared__ __bf16 sK[64 * 32];
  int tid = threadIdx.x, w = tid >> 6, l = tid & 63;
  int lr = l & 15, lk = (l >> 4) * 8;
  int srow = tid >> 3, scol = (tid & 7) * 8;
  f32x4 acc[4] = {};

  for (int kc = 0; kc < 1024; kc += 32) {
    size_t grow = (size_t)(k0base + kc + srow) * 3072;
    bf16x8 qv = *(const bf16x8*)(qkv + grow + h * 64 + scol);
    bf16x8 kv = *(const bf16x8*)(qkv + grow + 1024 + h * 64 + scol);
    __syncthreads();
    #pragma unroll
    for (int j = 0; j < 8; ++j) {
      sQ[(scol + j) * 32 + srow] = qv[j];
      sK[(scol + j) * 32 + srow] = kv[j];
    }
    __syncthreads();
    bf16x8 a = *(const bf16x8*)(sQ + (w * 16 + lr) * 32 + lk);
    #pragma unroll
    for (int n = 0; n < 4; ++n) {
      bf16x8 bb = *(const bf16x8*)(sK + (n * 16 + lr) * 32 + lk);
      acc[n] = __builtin_amdgcn_mfma_f32_16x16x32_bf16(a, bb, acc[n], 0, 0, 0);
    }
  }
  float* cbase = ctx + (size_t)h * 64 * 64;
  #pragma unroll
  for (int n = 0; n < 4; ++n) {
    int col = n * 16 + lr;
    #pragma unroll
    for (int j = 0; j < 4; ++j) {
      int row = w * 16 + (l >> 4) * 4 + j;
      atomicAdd(cbase + row * 64 + col, acc[n][j]);
    }
  }
}

__global__ __launch_bounds__(256) void pv_gemm(const __bf16* __restrict__ qkv,
                                               const float* __restrict__ ctx,
                                               const float* __restrict__ S,
                                               __bf16* __restrict__ outpv) {
  qkv   += (size_t)blockIdx.z * 4096 * 3072;
  ctx   += (size_t)blockIdx.z * 16 * 4096;
  S     += (size_t)blockIdx.z * 1024;
  outpv += (size_t)blockIdx.z * 4096 * 1024;
  int h = blockIdx.y;
  int row0 = blockIdx.x * 128;
  __shared__ __bf16 sC[64 * 64];
  int tid = threadIdx.x;
  const float* cb = ctx + (size_t)h * 4096;
  for (int i = tid; i < 4096; i += 256) {
    int d = i >> 6, e = i & 63;
    sC[e * 64 + d] = (__bf16)cb[i];
  }
  __syncthreads();
  int w = tid >> 6, l = tid & 63;
  int lr = l & 15, lk = (l >> 4) * 8;
  f32x4 acc[2][4] = {};
  const __bf16* vbase = qkv + 2048 + h * 64;
  #pragma unroll
  for (int kk = 0; kk < 64; kk += 32) {
    #pragma unroll
    for (int m = 0; m < 2; ++m) {
      int r = row0 + w * 32 + m * 16 + lr;
      bf16x8 a = *(const bf16x8*)(vbase + (size_t)r * 3072 + kk + lk);
      #pragma unroll
      for (int n = 0; n < 4; ++n) {
        bf16x8 bb = *(const bf16x8*)(sC + (n * 16 + lr) * 64 + kk + lk);
        acc[m][n] = __builtin_amdgcn_mfma_f32_16x16x32_bf16(a, bb, acc[m][n], 0, 0, 0);
      }
    }
  }
  #pragma unroll
  for (int m = 0; m < 2; ++m) {
    int rb = row0 + w * 32 + m * 16 + (l >> 4) * 4;
    #pragma unroll
    for (int n = 0; n < 4; ++n) {
      int e = n * 16 + lr;
      float inv = 1.0f / S[h * 64 + e];
      #pragma unroll
      for (int j = 0; j < 4; ++j)
        outpv[(size_t)(rb + j) * 1024 + h * 64 + e] = (__bf16)(acc[m][n][j] * inv);
    }
  }
}

// ---------------- LayerNorm (row of 1024, bf16 in -> bf16 out) ----------------
__global__ __launch_bounds__(256) void layernorm_k(const __bf16* __restrict__ attn,
                                                   const float* __restrict__ g,
                                                   const float* __restrict__ beta,
                                                   __bf16* __restrict__ out) {
  int row = blockIdx.x;
  int t = threadIdx.x;
  bf16x4 v4 = *(const bf16x4*)(attn + (size_t)row * 1024 + t * 4);
  float v0 = (float)v4[0], v1 = (float)v4[1], v2 = (float)v4[2], v3 = (float)v4[3];
  float s = v0 + v1 + v2 + v3;
  float ss = v0 * v0 + v1 * v1 + v2 * v2 + v3 * v3;
  #pragma unroll
  for (int sh = 32; sh; sh >>= 1) { s += __shfl_xor(s, sh); ss += __shfl_xor(ss, sh); }
  __shared__ float red[8];
  int w = t >> 6, l = t & 63;
  if (l == 0) { red[w] = s; red[4 + w] = ss; }
  __syncthreads();
  s = red[0] + red[1] + red[2] + red[3];
  ss = red[4] + red[5] + red[6] + red[7];
  float mu = s * (1.f / 1024.f);
  float var = ss * (1.f / 1024.f) - mu * mu;
  float rstd = rsqrtf(var + 1e-5f);
  float4 gg = *(const float4*)(g + t * 4);
  float4 bb = *(const float4*)(beta + t * 4);
  bf16x4 o;
  o[0] = (__bf16)((v0 - mu) * rstd * gg.x + bb.x);
  o[1] = (__bf16)((v1 - mu) * rstd * gg.y + bb.y);
  o[2] = (__bf16)((v2 - mu) * rstd * gg.z + bb.z);
  o[3] = (__bf16)((v3 - mu) * rstd * gg.w + bb.w);
  *(bf16x4*)(out + (size_t)row * 1024 + t * 4) = o;
}

// ---------------- launch ----------------

extern "C" void kernel_launch(void* const* d_in, const int* in_sizes, int n_in,
                              void* d_out, int out_size, void* d_ws, size_t ws_size,
                              hipStream_t stream) {
  const float* x     = (const float*)d_in[0];
  const float* W_qkv = (const float*)d_in[1];
  const float* W_out = (const float*)d_in[2];
  const float* b_out = (const float*)d_in[3];
  const float* ln_g  = (const float*)d_in[4];
  const float* ln_b  = (const float*)d_in[5];
  const float* W1    = (const float*)d_in[6];
  const float* b1    = (const float*)d_in[7];
  const float* W2    = (const float*)d_in[8];
  const float* b2    = (const float*)d_in[9];

  char* ws = (char*)d_ws;
  size_t off = 0;
  auto alloc = [&](size_t bytes) { void* p = ws + off; off += (bytes + 255) & ~(size_t)255; return p; };

  __bf16* wqkvT = (__bf16*)alloc(3072ull * 1024 * 2);
  __bf16* woutT = (__bf16*)alloc(1024ull * 1024 * 2);
  __bf16* w1T   = (__bf16*)alloc(4096ull * 1024 * 2);
  __bf16* w2T   = (__bf16*)alloc(1024ull * 4096 * 2);

  cvt_wT<<<dim3(32, 96), dim3(32, 8), 0, stream>>>(W_qkv, wqkvT, 1024, 3072);
  cvt_wT<<<dim3(32, 32), dim3(32, 8), 0, stream>>>(W_out, woutT, 1024, 1024);
  cvt_wT<<<dim3(32, 128), dim3(32, 8), 0, stream>>>(W1, w1T, 1024, 4096);
  cvt_wT<<<dim3(128, 32), dim3(32, 8), 0, stream>>>(W2, w2T, 4096, 1024);

  const size_t FULL_NEED = 196ull << 20;

  if (ws_size >= FULL_NEED) {
    // ---------- FULL path ----------
    float*  Sctx  = (float*)alloc((4096ull + 4 * 16 * 4096) * 4);
    __bf16* xb    = (__bf16*)alloc(16384ull * 1024 * 2);
    __bf16* qkv   = (__bf16*)alloc(16384ull * 3072 * 2);
    __bf16* outpv = (__bf16*)alloc(16384ull * 1024 * 2);

    float* S   = Sctx;
    float* ctx = Sctx + 4096;
    __bf16* attn = (__bf16*)((char*)qkv + (64ull << 20));
    __bf16* hln  = xb;
    __bf16* ffn1 = qkv;

    cvt_f32_bf16<<<16384, 256, 0, stream>>>(x, xb, 16777216L);
    zero_f32<<<260, 256, 0, stream>>>(Sctx, 266240);

    gemm256<EPI_BF16><<<dim3(64, 12), 512, 0, stream>>>(xb, wqkvT, qkv, nullptr, 16384, 3072, 1024);
    q_softmax<<<dim3(16384, 1, 4), 256, 0, stream>>>(qkv);
    k_exp<<<dim3(4, 32, 4), 256, 0, stream>>>(qkv, S);
    ctx_gemm<<<dim3(16, 4, 4), 256, 0, stream>>>(qkv, ctx);
    pv_gemm<<<dim3(32, 16, 4), 256, 0, stream>>>(qkv, ctx, S, outpv);

    gemm256<EPI_BF16_BIAS><<<dim3(64, 4), 512, 0, stream>>>(outpv, woutT, attn, b_out, 16384, 1024, 1024);
    layernorm_k<<<16384, 256, 0, stream>>>(attn, ln_g, ln_b, hln);
    gemm256<EPI_BF16_SILU><<<dim3(64, 16), 512, 0, stream>>>(hln, w1T, ffn1, b1, 16384, 4096, 1024);
    gemm256<EPI_F32_BIAS><<<dim3(64, 4), 512, 0, stream>>>(ffn1, w2T, (float*)d_out, b2, 16384, 1024, 4096);
  } else {
    // ---------- CHUNKED fallback (~112 MiB) ----------
    float*  Sctx  = (float*)alloc(66560ull * 4);
    __bf16* xb    = (__bf16*)alloc(16384ull * 1024 * 2);
    __bf16* outpv = (__bf16*)alloc(16384ull * 1024 * 2);
    __bf16* qkv_b = (__bf16*)alloc(4096ull * 3072 * 2);

    float* S   = Sctx;
    float* ctx = Sctx + 1024;
    __bf16* attn = xb;
    __bf16* hln  = outpv;
    __bf16* fchunk = xb;

    cvt_f32_bf16<<<16384, 256, 0, stream>>>(x, xb, 16777216L);

    for (int b = 0; b < 4; ++b) {
      const __bf16* xb_b = xb + (size_t)b * 4096 * 1024;
      gemm256<EPI_BF16><<<dim3(16, 12), 512, 0, stream>>>(xb_b, wqkvT, qkv_b, nullptr, 4096, 3072, 1024);
      zero_f32<<<65, 256, 0, stream>>>(Sctx, 66560);
      q_softmax<<<dim3(16384, 1, 1), 256, 0, stream>>>(qkv_b);
      k_exp<<<dim3(4, 32, 1), 256, 0, stream>>>(qkv_b, S);
      ctx_gemm<<<dim3(16, 4, 1), 256, 0, stream>>>(qkv_b, ctx);
      pv_gemm<<<dim3(32, 16, 1), 256, 0, stream>>>(qkv_b, ctx, S, outpv + (size_t)b * 4096 * 1024);
    }

    gemm256<EPI_BF16_BIAS><<<dim3(64, 4), 512, 0, stream>>>(outpv, woutT, attn, b_out, 16384, 1024, 1024);
    layernorm_k<<<16384, 256, 0, stream>>>(attn, ln_g, ln_b, hln);

    for (int c = 0; c < 4; ++c) {
      const __bf16* h_c = hln + (size_t)c * 4096 * 1024;
      float* out_c = (float*)d_out + (size_t)c * 4096 * 1024;
      gemm256<EPI_BF16_SILU><<<dim3(16, 16), 512, 0, stream>>>(h_c, w1T, fchunk, b1, 4096, 4096, 1024);
      gemm256<EPI_F32_BIAS><<<dim3(16, 4), 512, 0, stream>>>(fchunk, w2T, out_c, b2, 4096, 1024, 4096);
    }
  }
}

// Round 5
// 587.544 us; speedup vs baseline: 1.6485x; 1.0096x over previous
//
#include <hip/hip_runtime.h>
#include <hip/hip_bf16.h>

typedef __bf16 bf16x8 __attribute__((ext_vector_type(8)));
typedef __bf16 bf16x4 __attribute__((ext_vector_type(4)));
typedef float  f32x4  __attribute__((ext_vector_type(4)));

#define GLOAD_LDS16(gp, lp) \
  __builtin_amdgcn_global_load_lds((const __attribute__((address_space(1))) void*)(gp), \
                                   (__attribute__((address_space(3))) void*)(lp), 16, 0, 0)

// ---------------- utility kernels ----------------

__global__ __launch_bounds__(256) void zero_f32(float* __restrict__ p, int n) {
  int i = (blockIdx.x * 256 + threadIdx.x) * 4;
  if (i < n) *(float4*)(p + i) = make_float4(0.f, 0.f, 0.f, 0.f);
}

__global__ __launch_bounds__(256) void cvt_f32_bf16(const float* __restrict__ in,
                                                    __bf16* __restrict__ out, long n) {
  long i = ((long)blockIdx.x * 256 + threadIdx.x) * 4;
  if (i >= n) return;
  float4 v = *(const float4*)(in + i);
  bf16x4 o;
  o[0] = (__bf16)v.x; o[1] = (__bf16)v.y; o[2] = (__bf16)v.z; o[3] = (__bf16)v.w;
  *(bf16x4*)(out + i) = o;
}

// W [K][N] f32 row-major  ->  WT [N][K] bf16 row-major
__global__ __launch_bounds__(256) void cvt_wT(const float* __restrict__ W,
                                              __bf16* __restrict__ WT, int K, int N) {
  __shared__ float t[32][33];
  int k0 = blockIdx.x * 32, n0 = blockIdx.y * 32;
  int tx = threadIdx.x, ty = threadIdx.y;   // block (32,8)
  #pragma unroll
  for (int i = 0; i < 32; i += 8)
    t[ty + i][tx] = W[(size_t)(k0 + ty + i) * N + n0 + tx];
  __syncthreads();
  #pragma unroll
  for (int i = 0; i < 32; i += 8)
    WT[(size_t)(n0 + ty + i) * K + k0 + tx] = (__bf16)t[tx][ty + i];
}

// ---------------- 256x256 deep-pipelined GEMM:  C[M,N] = A[M,K] @ BT[N,K]^T ----
// 512 threads (8 waves 2x4), BK=32, quad-buffered LDS (128 KiB), counted vmcnt,
// raw barriers, setprio around MFMA clusters.
// LDS chunk (row,oct) holds source octet oct^((row>>1)&3): spreads a quarter-wave's
// 16 rows across all 8 bank-quads (2 lanes/quad = free). Same involution on read.

enum { EPI_BF16 = 0, EPI_F32_BIAS = 1, EPI_BF16_SILU = 2, EPI_BF16_BIAS = 3 };

template <int EPI>
__global__ __launch_bounds__(512, 1)
void gemm256(const __bf16* __restrict__ A, const __bf16* __restrict__ B,
             void* __restrict__ Cout, const float* __restrict__ bias,
             int M, int N, int K) {
  __shared__ __bf16 lds[4 * 16384];   // 4 bufs x (A 8192 + B 8192) elems = 128 KiB
  const int tid = threadIdx.x;
  const int w = tid >> 6, l = tid & 63;
  const int brow = blockIdx.x * 256;
  const int bcol = blockIdx.y * 256;
  const int wr = w >> 2, wc = w & 3;           // wave grid 2x4
  const int lr = l & 15, lk = (l >> 4) * 8;
  const int rdo = ((lk >> 3) ^ ((lr >> 1) & 3)) << 3;  // swizzled read octet
  const int NT = K >> 5;

  // staging lane geometry: chunk (rr, oct); source octet = oct ^ ((rr>>1)&3)
  const int rr = w * 16 + (l >> 2);
  const int oct = l & 3;
  const int soct = oct ^ ((rr >> 1) & 3);
  const __bf16* gA0 = A + (size_t)(brow + rr) * K + soct * 8;
  const __bf16* gA1 = A + (size_t)(brow + 128 + rr) * K + soct * 8;
  const __bf16* gB0 = B + (size_t)(bcol + rr) * K + soct * 8;
  const __bf16* gB1 = B + (size_t)(bcol + 128 + rr) * K + soct * 8;
  __bf16* const ldsw = lds + w * 512;   // wave-uniform dest base

  f32x4 acc[8][4] = {};

  auto stage = [&](int buf) {
    __bf16* d = ldsw + buf * 16384;
    GLOAD_LDS16(gA0, d);
    GLOAD_LDS16(gA1, d + 4096);
    GLOAD_LDS16(gB0, d + 8192);
    GLOAD_LDS16(gB1, d + 12288);
    gA0 += 32; gA1 += 32; gB0 += 32; gB1 += 32;
  };

  // prologue: stage tiles 0,1,2
  stage(0); stage(1); stage(2);

  // per-lane LDS fragment bases (elems); frag m at +m*512, buffer at +(t&3)*16384
  const int abase = (wr * 128 + lr) * 32 + rdo;
  const int bbase = 8192 + (wc * 64 + lr) * 32 + rdo;

  for (int t = 0; t < NT; ++t) {
    if (t + 2 < NT)      asm volatile("s_waitcnt vmcnt(8)" ::: "memory");
    else if (t + 1 < NT) asm volatile("s_waitcnt vmcnt(4)" ::: "memory");
    else                 asm volatile("s_waitcnt vmcnt(0)" ::: "memory");
    __builtin_amdgcn_s_barrier();
    if (t + 3 < NT) stage((t + 3) & 3);

    const __bf16* sA = lds + (t & 3) * 16384 + abase;
    const __bf16* sB = lds + (t & 3) * 16384 + bbase;

    bf16x8 bfr[4], afr[4];
    #pragma unroll
    for (int n = 0; n < 4; ++n)
      bfr[n] = *(const bf16x8*)(sB + n * 512);
    #pragma unroll
    for (int m = 0; m < 4; ++m)
      afr[m] = *(const bf16x8*)(sA + m * 512);

    __builtin_amdgcn_s_setprio(1);
    #pragma unroll
    for (int m = 0; m < 4; ++m)
      #pragma unroll
      for (int n = 0; n < 4; ++n)
        acc[m][n] = __builtin_amdgcn_mfma_f32_16x16x32_bf16(afr[m], bfr[n], acc[m][n], 0, 0, 0);
    __builtin_amdgcn_s_setprio(0);

    #pragma unroll
    for (int m = 0; m < 4; ++m)
      afr[m] = *(const bf16x8*)(sA + (m + 4) * 512);

    __builtin_amdgcn_s_setprio(1);
    #pragma unroll
    for (int m = 0; m < 4; ++m)
      #pragma unroll
      for (int n = 0; n < 4; ++n)
        acc[m + 4][n] = __builtin_amdgcn_mfma_f32_16x16x32_bf16(afr[m], bfr[n], acc[m + 4][n], 0, 0, 0);
    __builtin_amdgcn_s_setprio(0);
  }

  // epilogue
  #pragma unroll
  for (int m = 0; m < 8; ++m) {
    int row0 = brow + wr * 128 + m * 16 + (l >> 4) * 4;
    #pragma unroll
    for (int n = 0; n < 4; ++n) {
      int col = bcol + wc * 64 + n * 16 + lr;
      float bv = (EPI == EPI_BF16) ? 0.f : bias[col];
      #pragma unroll
      for (int j = 0; j < 4; ++j) {
        float v = acc[m][n][j];
        size_t off = (size_t)(row0 + j) * N + col;
        if (EPI == EPI_BF16) {
          ((__bf16*)Cout)[off] = (__bf16)v;
        } else if (EPI == EPI_F32_BIAS) {
          ((float*)Cout)[off] = v + bv;
        } else if (EPI == EPI_BF16_BIAS) {
          ((__bf16*)Cout)[off] = (__bf16)(v + bv);
        } else {
          float z = v + bv;
          ((__bf16*)Cout)[off] = (__bf16)(z / (1.f + __expf(-z)));
        }
      }
    }
  }
}

// ---------------- attention pieces ----------------
// All take a batch index from blockIdx.z (z=0 == per-batch pointers, validated path).

__global__ __launch_bounds__(256) void q_softmax(__bf16* __restrict__ qkv) {
  qkv += (size_t)blockIdx.z * 4096 * 3072;
  int wg = blockIdx.x * 4 + (threadIdx.x >> 6);
  int l = threadIdx.x & 63;
  int row = wg >> 4, h = wg & 15;
  __bf16* p = qkv + (size_t)row * 3072 + h * 64 + l;
  float v = (float)*p * 0.125f;
  float m = v;
  #pragma unroll
  for (int s = 32; s; s >>= 1) m = fmaxf(m, __shfl_xor(m, s));
  float e = __expf(v - m);
  float sum = e;
  #pragma unroll
  for (int s = 32; s; s >>= 1) sum += __shfl_xor(sum, s);
  *p = (__bf16)(e / sum);
}

__global__ __launch_bounds__(256) void k_exp(__bf16* __restrict__ qkv, float* __restrict__ S) {
  qkv += (size_t)blockIdx.z * 4096 * 3072;
  S   += (size_t)blockIdx.z * 1024;
  int c = blockIdx.x * 256 + threadIdx.x;
  int n0 = blockIdx.y * 128;
  float sum = 0.f;
  __bf16* base = qkv + (size_t)n0 * 3072 + 1024 + c;
  for (int i = 0; i < 128; ++i) {
    __bf16* p = base + (size_t)i * 3072;
    float e = __expf((float)*p);
    __bf16 eb = (__bf16)e;
    *p = eb;
    sum += (float)eb;
  }
  atomicAdd(&S[c], sum);
}

__global__ __launch_bounds__(256) void ctx_gemm(const __bf16* __restrict__ qkv,
                                                float* __restrict__ ctx) {
  qkv += (size_t)blockIdx.z * 4096 * 3072;
  ctx += (size_t)blockIdx.z * 16 * 4096;
  int h = blockIdx.x;
  int k0base = blockIdx.y * 1024;
  __shared__ __bf16 sQ[64 * 32];
  __shared__ __bf16 sK[64 * 32];
  int tid = threadIdx.x, w = tid >> 6, l = tid & 63;
  int lr = l & 15, lk = (l >> 4) * 8;
  int srow = tid >> 3, scol = (tid & 7) * 8;
  f32x4 acc[4] = {};

  for (int kc = 0; kc < 1024; kc += 32) {
    size_t grow = (size_t)(k0base + kc + srow) * 3072;
    bf16x8 qv = *(const bf16x8*)(qkv + grow + h * 64 + scol);
    bf16x8 kv = *(const bf16x8*)(qkv + grow + 1024 + h * 64 + scol);
    __syncthreads();
    #pragma unroll
    for (int j = 0; j < 8; ++j) {
      sQ[(scol + j) * 32 + srow] = qv[j];
      sK[(scol + j) * 32 + srow] = kv[j];
    }
    __syncthreads();
    bf16x8 a = *(const bf16x8*)(sQ + (w * 16 + lr) * 32 + lk);
    #pragma unroll
    for (int n = 0; n < 4; ++n) {
      bf16x8 bb = *(const bf16x8*)(sK + (n * 16 + lr) * 32 + lk);
      acc[n] = __builtin_amdgcn_mfma_f32_16x16x32_bf16(a, bb, acc[n], 0, 0, 0);
    }
  }
  float* cbase = ctx + (size_t)h * 64 * 64;
  #pragma unroll
  for (int n = 0; n < 4; ++n) {
    int col = n * 16 + lr;
    #pragma unroll
    for (int j = 0; j < 4; ++j) {
      int row = w * 16 + (l >> 4) * 4 + j;
      atomicAdd(cbase + row * 64 + col, acc[n][j]);
    }
  }
}

__global__ __launch_bounds__(256) void pv_gemm(const __bf16* __restrict__ qkv,
                                               const float* __restrict__ ctx,
                                               const float* __restrict__ S,
                                               __bf16* __restrict__ outpv) {
  qkv   += (size_t)blockIdx.z * 4096 * 3072;
  ctx   += (size_t)blockIdx.z * 16 * 4096;
  S     += (size_t)blockIdx.z * 1024;
  outpv += (size_t)blockIdx.z * 4096 * 1024;
  int h = blockIdx.y;
  int row0 = blockIdx.x * 128;
  __shared__ __bf16 sC[64 * 64];
  int tid = threadIdx.x;
  const float* cb = ctx + (size_t)h * 4096;
  for (int i = tid; i < 4096; i += 256) {
    int d = i >> 6, e = i & 63;
    sC[e * 64 + d] = (__bf16)cb[i];
  }
  __syncthreads();
  int w = tid >> 6, l = tid & 63;
  int lr = l & 15, lk = (l >> 4) * 8;
  f32x4 acc[2][4] = {};
  const __bf16* vbase = qkv + 2048 + h * 64;
  #pragma unroll
  for (int kk = 0; kk < 64; kk += 32) {
    #pragma unroll
    for (int m = 0; m < 2; ++m) {
      int r = row0 + w * 32 + m * 16 + lr;
      bf16x8 a = *(const bf16x8*)(vbase + (size_t)r * 3072 + kk + lk);
      #pragma unroll
      for (int n = 0; n < 4; ++n) {
        bf16x8 bb = *(const bf16x8*)(sC + (n * 16 + lr) * 64 + kk + lk);
        acc[m][n] = __builtin_amdgcn_mfma_f32_16x16x32_bf16(a, bb, acc[m][n], 0, 0, 0);
      }
    }
  }
  #pragma unroll
  for (int m = 0; m < 2; ++m) {
    int rb = row0 + w * 32 + m * 16 + (l >> 4) * 4;
    #pragma unroll
    for (int n = 0; n < 4; ++n) {
      int e = n * 16 + lr;
      float inv = 1.0f / S[h * 64 + e];
      #pragma unroll
      for (int j = 0; j < 4; ++j)
        outpv[(size_t)(rb + j) * 1024 + h * 64 + e] = (__bf16)(acc[m][n][j] * inv);
    }
  }
}

// ---------------- LayerNorm (row of 1024, bf16 in -> bf16 out) ----------------
__global__ __launch_bounds__(256) void layernorm_k(const __bf16* __restrict__ attn,
                                                   const float* __restrict__ g,
                                                   const float* __restrict__ beta,
                                                   __bf16* __restrict__ out) {
  int row = blockIdx.x;
  int t = threadIdx.x;
  bf16x4 v4 = *(const bf16x4*)(attn + (size_t)row * 1024 + t * 4);
  float v0 = (float)v4[0], v1 = (float)v4[1], v2 = (float)v4[2], v3 = (float)v4[3];
  float s = v0 + v1 + v2 + v3;
  float ss = v0 * v0 + v1 * v1 + v2 * v2 + v3 * v3;
  #pragma unroll
  for (int sh = 32; sh; sh >>= 1) { s += __shfl_xor(s, sh); ss += __shfl_xor(ss, sh); }
  __shared__ float red[8];
  int w = t >> 6, l = t & 63;
  if (l == 0) { red[w] = s; red[4 + w] = ss; }
  __syncthreads();
  s = red[0] + red[1] + red[2] + red[3];
  ss = red[4] + red[5] + red[6] + red[7];
  float mu = s * (1.f / 1024.f);
  float var = ss * (1.f / 1024.f) - mu * mu;
  float rstd = rsqrtf(var + 1e-5f);
  float4 gg = *(const float4*)(g + t * 4);
  float4 bb = *(const float4*)(beta + t * 4);
  bf16x4 o;
  o[0] = (__bf16)((v0 - mu) * rstd * gg.x + bb.x);
  o[1] = (__bf16)((v1 - mu) * rstd * gg.y + bb.y);
  o[2] = (__bf16)((v2 - mu) * rstd * gg.z + bb.z);
  o[3] = (__bf16)((v3 - mu) * rstd * gg.w + bb.w);
  *(bf16x4*)(out + (size_t)row * 1024 + t * 4) = o;
}

// ---------------- launch ----------------

extern "C" void kernel_launch(void* const* d_in, const int* in_sizes, int n_in,
                              void* d_out, int out_size, void* d_ws, size_t ws_size,
                              hipStream_t stream) {
  const float* x     = (const float*)d_in[0];
  const float* W_qkv = (const float*)d_in[1];
  const float* W_out = (const float*)d_in[2];
  const float* b_out = (const float*)d_in[3];
  const float* ln_g  = (const float*)d_in[4];
  const float* ln_b  = (const float*)d_in[5];
  const float* W1    = (const float*)d_in[6];
  const float* b1    = (const float*)d_in[7];
  const float* W2    = (const float*)d_in[8];
  const float* b2    = (const float*)d_in[9];

  char* ws = (char*)d_ws;
  size_t off = 0;
  auto alloc = [&](size_t bytes) { void* p = ws + off; off += (bytes + 255) & ~(size_t)255; return p; };

  __bf16* wqkvT = (__bf16*)alloc(3072ull * 1024 * 2);
  __bf16* woutT = (__bf16*)alloc(1024ull * 1024 * 2);
  __bf16* w1T   = (__bf16*)alloc(4096ull * 1024 * 2);
  __bf16* w2T   = (__bf16*)alloc(1024ull * 4096 * 2);

  cvt_wT<<<dim3(32, 96), dim3(32, 8), 0, stream>>>(W_qkv, wqkvT, 1024, 3072);
  cvt_wT<<<dim3(32, 32), dim3(32, 8), 0, stream>>>(W_out, woutT, 1024, 1024);
  cvt_wT<<<dim3(32, 128), dim3(32, 8), 0, stream>>>(W1, w1T, 1024, 4096);
  cvt_wT<<<dim3(128, 32), dim3(32, 8), 0, stream>>>(W2, w2T, 4096, 1024);

  const size_t FULL_NEED = 196ull << 20;

  if (ws_size >= FULL_NEED) {
    // ---------- FULL path ----------
    float*  Sctx  = (float*)alloc((4096ull + 4 * 16 * 4096) * 4);
    __bf16* xb    = (__bf16*)alloc(16384ull * 1024 * 2);
    __bf16* qkv   = (__bf16*)alloc(16384ull * 3072 * 2);
    __bf16* outpv = (__bf16*)alloc(16384ull * 1024 * 2);

    float* S   = Sctx;
    float* ctx = Sctx + 4096;
    __bf16* attn = (__bf16*)((char*)qkv + (64ull << 20));
    __bf16* hln  = xb;
    __bf16* ffn1 = qkv;

    cvt_f32_bf16<<<16384, 256, 0, stream>>>(x, xb, 16777216L);
    zero_f32<<<260, 256, 0, stream>>>(Sctx, 266240);

    gemm256<EPI_BF16><<<dim3(64, 12), 512, 0, stream>>>(xb, wqkvT, qkv, nullptr, 16384, 3072, 1024);
    q_softmax<<<dim3(16384, 1, 4), 256, 0, stream>>>(qkv);
    k_exp<<<dim3(4, 32, 4), 256, 0, stream>>>(qkv, S);
    ctx_gemm<<<dim3(16, 4, 4), 256, 0, stream>>>(qkv, ctx);
    pv_gemm<<<dim3(32, 16, 4), 256, 0, stream>>>(qkv, ctx, S, outpv);

    gemm256<EPI_BF16_BIAS><<<dim3(64, 4), 512, 0, stream>>>(outpv, woutT, attn, b_out, 16384, 1024, 1024);
    layernorm_k<<<16384, 256, 0, stream>>>(attn, ln_g, ln_b, hln);
    gemm256<EPI_BF16_SILU><<<dim3(64, 16), 512, 0, stream>>>(hln, w1T, ffn1, b1, 16384, 4096, 1024);
    gemm256<EPI_F32_BIAS><<<dim3(64, 4), 512, 0, stream>>>(ffn1, w2T, (float*)d_out, b2, 16384, 1024, 4096);
  } else {
    // ---------- CHUNKED fallback (~112 MiB) ----------
    float*  Sctx  = (float*)alloc(66560ull * 4);
    __bf16* xb    = (__bf16*)alloc(16384ull * 1024 * 2);
    __bf16* outpv = (__bf16*)alloc(16384ull * 1024 * 2);
    __bf16* qkv_b = (__bf16*)alloc(4096ull * 3072 * 2);

    float* S   = Sctx;
    float* ctx = Sctx + 1024;
    __bf16* attn = xb;
    __bf16* hln  = outpv;
    __bf16* fchunk = xb;

    cvt_f32_bf16<<<16384, 256, 0, stream>>>(x, xb, 16777216L);

    for (int b = 0; b < 4; ++b) {
      const __bf16* xb_b = xb + (size_t)b * 4096 * 1024;
      gemm256<EPI_BF16><<<dim3(16, 12), 512, 0, stream>>>(xb_b, wqkvT, qkv_b, nullptr, 4096, 3072, 1024);
      zero_f32<<<65, 256, 0, stream>>>(Sctx, 66560);
      q_softmax<<<dim3(16384, 1, 1), 256, 0, stream>>>(qkv_b);
      k_exp<<<dim3(4, 32, 1), 256, 0, stream>>>(qkv_b, S);
      ctx_gemm<<<dim3(16, 4, 1), 256, 0, stream>>>(qkv_b, ctx);
      pv_gemm<<<dim3(32, 16, 1), 256, 0, stream>>>(qkv_b, ctx, S, outpv + (size_t)b * 4096 * 1024);
    }

    gemm256<EPI_BF16_BIAS><<<dim3(64, 4), 512, 0, stream>>>(outpv, woutT, attn, b_out, 16384, 1024, 1024);
    layernorm_k<<<16384, 256, 0, stream>>>(attn, ln_g, ln_b, hln);

    for (int c = 0; c < 4; ++c) {
      const __bf16* h_c = hln + (size_t)c * 4096 * 1024;
      float* out_c = (float*)d_out + (size_t)c * 4096 * 1024;
      gemm256<EPI_BF16_SILU><<<dim3(16, 16), 512, 0, stream>>>(h_c, w1T, fchunk, b1, 4096, 4096, 1024);
      gemm256<EPI_F32_BIAS><<<dim3(16, 4), 512, 0, stream>>>(fchunk, w2T, out_c, b2, 4096, 1024, 4096);
    }
  }
}